// Round 1
// baseline (113.728 us; speedup 1.0000x reference)
//
#include <hip/hip_runtime.h>

// Fully-fused LSA: transpose + 5x5 stencil + (Wv @ sT) GEMM + residual in ONE
// kernel. Index algebra for stencil and MFMA phases is verbatim from the
// HW-verified 3-kernel pipeline (R2/R4, 110.9 us); this round eliminates the
// two extra launches and the fT/sT HBM round-trips.
//   phase 0: stage halo (8x24 px, 128 ch) fmap f32 -> hs bf16 (in-block
//            transpose; lane-local row-runs reuse L1) + stage attn
//   phase 1: 5x5 stencil, acc f32[32]/thread (4 thr/px) -> pack -> sv (LDS)
//            + prefetch Wv f32 into regs
//   phase 2: cvt Wv -> bf16 into dead hs region; per-wave 16px x 128ch MFMA
//            (verified lsa_gemm fragment mapping, mg = 0..7)
//   phase 3: out = fmap + gamma * acc   (f32 residual from global)
// B=4, C=128, H=64, W=128, L=25. LDS 76.0 KB -> 2 blocks/CU.

namespace {
constexpr int Bn = 4, Cn = 128, Hn = 64, Wn = 128, Ln = 25;
constexpr int HWn = Hn * Wn;  // 8192

constexpr int TY = 4, TX = 16;   // output tile: 64 px/block
constexpr int HY = 8, HX = 24;   // halo rows x cols (y0-2..y0+5, x0-4..x0+19)
constexpr int RS = 136;          // hs row stride in halves (272B, 16B-aligned)
constexpr int SVS = 136;         // sv row stride in halves
constexpr int WVS = 136;         // wv row stride in halves (hs region reuse)

typedef __attribute__((ext_vector_type(8))) short short8;
typedef __attribute__((ext_vector_type(4))) float f32x4;

__device__ inline unsigned short f2bf(float f) {
    unsigned u = __float_as_uint(f);
    return (unsigned short)((u + 0x7fffu + ((u >> 16) & 1u)) >> 16);  // RNE
}

__global__ __launch_bounds__(256) void lsa_fused(
    const float* __restrict__ attn, const float* __restrict__ fmap,
    const float* __restrict__ Wv, const float* __restrict__ gamma,
    float* __restrict__ out)
{
    // hs: halo bf16 [dy][hx][c] (52.2 KB) -- reused for Wv bf16 after stencil
    __shared__ alignas(16) unsigned short hs[HY * HX * RS];
    __shared__ alignas(16) unsigned short sv[TY * TX * SVS];  // 17.4 KB
    __shared__ float at_s[TY * TX * Ln];                      // 6.4 KB

    const int tid = threadIdx.x;
    const int b = blockIdx.z;
    const int x0 = blockIdx.x * TX;
    const int y0 = blockIdx.y * TY;

    // ---- phase 0: halo stage with in-block transpose (f32 -> bf16) ----
    // wave-coherent: at step t all 64 lanes of a wave cover ONE halo pixel,
    // 64 channel-pairs; successive t walk hx -> each lane re-hits its own
    // 64B line (L1). 48 iters/thread.
    for (int i = tid; i < HY * HX * 64; i += 256) {
        const int px = i >> 6, cp = i & 63;
        const int dy = px / HX, hx = px - dy * HX;
        const int ry = min(max(y0 + dy - 2, 0), Hn - 1);
        const int gx = min(max(x0 + hx - 4, 0), Wn - 1);
        const size_t base = ((size_t)(b * Cn + 2 * cp)) * HWn + ry * Wn + gx;
        const float f0 = fmap[base];
        const float f1 = fmap[base + HWn];
        *(unsigned*)&hs[px * RS + 2 * cp] =
            (unsigned)f2bf(f0) | ((unsigned)f2bf(f1) << 16);
    }
    // stage attn [p][l] (coalesced 100B runs)
    for (int i = tid; i < TY * TX * Ln; i += 256) {
        const int p = i / Ln, l = i - p * Ln;
        const int n = (y0 + (p >> 4)) * Wn + x0 + (p & 15);
        at_s[i] = attn[((size_t)b * HWn + n) * Ln + l];
    }
    __syncthreads();

    // ---- phase 1: 5x5 stencil (verbatim verified inner loop) ----
    // thread map: xi = tid&15, kq = (tid>>4)&3 (32-ch group), yi = tid>>6
    const int xi = tid & 15, kq = (tid >> 4) & 3, yi = tid >> 6;
    const int p = yi * 16 + xi;
    float acc[32];
#pragma unroll
    for (int j = 0; j < 32; ++j) acc[j] = 0.f;

#pragma unroll
    for (int l = 0; l < Ln; ++l) {
        const int dy = l / 5, dx = l % 5;
        const float a = at_s[p * Ln + l];
        const unsigned short* row = &hs[((yi + dy) * HX + (2 + xi + dx)) * RS + kq * 32];
#pragma unroll
        for (int q = 0; q < 4; ++q) {
            uint4 u = *(const uint4*)&row[q * 8];
            const unsigned w[4] = {u.x, u.y, u.z, u.w};
#pragma unroll
            for (int e = 0; e < 4; ++e) {
                acc[q * 8 + 2 * e + 0] += a * __uint_as_float(w[e] << 16);
                acc[q * 8 + 2 * e + 1] += a * __uint_as_float(w[e] & 0xffff0000u);
            }
        }
    }
    // pack acc -> sv tile (bf16, k-contiguous per pixel); no barrier needed yet
    {
        unsigned short* dst = &sv[p * SVS + kq * 32];
#pragma unroll
        for (int q = 0; q < 4; ++q) {
            unsigned pk[4];
#pragma unroll
            for (int e = 0; e < 4; ++e)
                pk[e] = (unsigned)f2bf(acc[q * 8 + 2 * e]) |
                        ((unsigned)f2bf(acc[q * 8 + 2 * e + 1]) << 16);
            uint4 v; v.x = pk[0]; v.y = pk[1]; v.z = pk[2]; v.w = pk[3];
            *(uint4*)&dst[q * 8] = v;
        }
    }
    // prefetch Wv f32 (coalesced 1KB/wave-instr; L2-hot, same 64KB all blocks)
    float4 wq[16];
#pragma unroll
    for (int t = 0; t < 16; ++t)
        wq[t] = *(const float4*)&Wv[(size_t)(tid + t * 256) * 4];

    __syncthreads();  // halo reads done everywhere; sv writes visible

    // ---- phase 2a: Wv -> bf16 into dead hs region ----
#pragma unroll
    for (int t = 0; t < 16; ++t) {
        const int i4 = tid + t * 256;      // float4 index within Wv
        const int r = i4 >> 5;             // row (32 float4 per 128-col row)
        const int c = (i4 & 31) * 4;
        uint2 v;
        v.x = (unsigned)f2bf(wq[t].x) | ((unsigned)f2bf(wq[t].y) << 16);
        v.y = (unsigned)f2bf(wq[t].z) | ((unsigned)f2bf(wq[t].w) << 16);
        *(uint2*)&hs[r * WVS + c] = v;
    }
    __syncthreads();

    // ---- phase 2b: MFMA, verified lsa_gemm mapping (wave = 16 px x 128 ch) ----
    const int wave = tid >> 6, lane = tid & 63;
    const int m16 = lane & 15, q = lane >> 4;
    const int n = (y0 + wave) * Wn + x0 + m16;  // wave w owns pixel row y0+w
    const float g = gamma[0];

    short8 bfrag[4];
    {
        const unsigned short* srow = &sv[(wave * 16 + m16) * SVS + q * 8];
#pragma unroll
        for (int kk = 0; kk < 4; ++kk) bfrag[kk] = *(const short8*)(srow + kk * 32);
    }
    f32x4 accv[8];
#pragma unroll
    for (int t = 0; t < 8; ++t) { f32x4 z = {0.f, 0.f, 0.f, 0.f}; accv[t] = z; }

#pragma unroll
    for (int t = 0; t < 8; ++t) {
        const unsigned short* arow = &hs[(t * 16 + m16) * WVS + q * 8];
#pragma unroll
        for (int kk = 0; kk < 4; ++kk) {
            short8 af = *(const short8*)(arow + kk * 32);
            accv[t] = __builtin_amdgcn_mfma_f32_16x16x32_bf16(af, bfrag[kk], accv[t], 0, 0, 0);
        }
    }

    // ---- phase 3: residual epilogue (f32 fmap from global, L2-hot) ----
#pragma unroll
    for (int t = 0; t < 8; ++t) {
#pragma unroll
        for (int r = 0; r < 4; ++r) {
            const int c = t * 16 + q * 4 + r;
            const size_t idx = ((size_t)(b * Cn + c)) * HWn + n;
            out[idx] = fmap[idx] + g * accv[t][r];
        }
    }
}
}  // namespace

extern "C" void kernel_launch(void* const* d_in, const int* in_sizes, int n_in,
                              void* d_out, int out_size, void* d_ws, size_t ws_size,
                              hipStream_t stream) {
    const float* attn  = (const float*)d_in[0];
    const float* fmap  = (const float*)d_in[1];
    const float* Wv    = (const float*)d_in[2];
    const float* gamma = (const float*)d_in[3];
    float* out = (float*)d_out;

    dim3 grid(Wn / TX, Hn / TY, Bn);  // 8 x 16 x 4 = 512 blocks
    lsa_fused<<<grid, 256, 0, stream>>>(attn, fmap, Wv, gamma, out);
}

// Round 2
// 99.740 us; speedup vs baseline: 1.1403x; 1.1403x over previous
//
#include <hip/hip_runtime.h>

// Fully-fused LSA: transpose + 5x5 stencil + (Wv @ sT) GEMM + residual in ONE
// kernel. R1 (64us/dispatch) was VMEM-bound in phase 0: halo staging used
// per-channel scalar gathers (64 lines splayed per wave-instr). R2 restages
// the halo as channel-pair float4 runs (coalesced 96B runs, 4x fewer load
// instrs, 16x fewer lines per instr) writing packed bf16 pairs straight into
// the SAME hs layout. Stencil / sv pack / Wv MFMA / epilogue are verbatim the
// R1-verified code (absmax 0.125).
//   phase 0: halo fmap f32 -> hs bf16 [px][c] via float4 ch-pair staging
//            + stage attn (linear coalesced)
//   phase 1: 5x5 stencil, acc f32[32]/thread (4 thr/px) -> pack -> sv (LDS)
//            + prefetch Wv f32 into regs
//   phase 2: cvt Wv -> bf16 into dead hs region; per-wave 16px x 128ch MFMA
//   phase 3: out = fmap + gamma * acc   (f32 residual from global)
// B=4, C=128, H=64, W=128, L=25. LDS 76.0 KB -> 2 blocks/CU.

namespace {
constexpr int Bn = 4, Cn = 128, Hn = 64, Wn = 128, Ln = 25;
constexpr int HWn = Hn * Wn;  // 8192

constexpr int TY = 4, TX = 16;   // output tile: 64 px/block
constexpr int HY = 8, HX = 24;   // halo rows x cols (y0-2..y0+5, x0-4..x0+19)
constexpr int RS = 136;          // hs row stride in halves (272B, 16B-aligned)
constexpr int SVS = 136;         // sv row stride in halves
constexpr int WVS = 136;         // wv row stride in halves (hs region reuse)

typedef __attribute__((ext_vector_type(8))) short short8;
typedef __attribute__((ext_vector_type(4))) float f32x4;

__device__ inline unsigned short f2bf(float f) {
    unsigned u = __float_as_uint(f);
    return (unsigned short)((u + 0x7fffu + ((u >> 16) & 1u)) >> 16);  // RNE
}

__global__ __launch_bounds__(256) void lsa_fused(
    const float* __restrict__ attn, const float* __restrict__ fmap,
    const float* __restrict__ Wv, const float* __restrict__ gamma,
    float* __restrict__ out)
{
    // hs: halo bf16 [px = dy*HX+hx][c] (52.2 KB) -- reused for Wv bf16 later
    __shared__ alignas(16) unsigned short hs[HY * HX * RS];
    __shared__ alignas(16) unsigned short sv[TY * TX * SVS];  // 17.4 KB
    __shared__ float at_s[TY * TX * Ln];                      // 6.4 KB

    const int tid = threadIdx.x;
    const int b = blockIdx.z;
    const int x0 = blockIdx.x * TX;
    const int y0 = blockIdx.y * TY;

    // ---- phase 0: halo stage, channel-pair float4 runs (f32 -> packed bf16) ----
    // work item i -> (k = gx-quad 0..5, cp = channel-pair 0..63, dy = 0..7).
    // Consecutive lanes walk k then cp: global side ~11 contiguous 96B runs
    // per wave-instr; LDS side banks (16k + cp + 4e) & 31 -> ~3-way.
    // Halo quads are fully in-range or fully clamped (W mult of 4, pad 4).
    for (int i = tid; i < HY * 64 * 6; i += 256) {  // 3072 items, 12 iters
        const int k = i % 6;
        const int r = i / 6;
        const int cp = r & 63;
        const int dy = r >> 6;
        const int ry = min(max(y0 + dy - 2, 0), Hn - 1);
        const int gxb = x0 - 4 + 4 * k;
        const size_t rowb = ((size_t)(b * Cn + 2 * cp)) * HWn + (size_t)ry * Wn;
        float4 va, vb;
        if (gxb < 0) {                       // only x0==0, k==0: replicate col 0
            const float s0 = fmap[rowb], s1 = fmap[rowb + HWn];
            va.x = va.y = va.z = va.w = s0;
            vb.x = vb.y = vb.z = vb.w = s1;
        } else if (gxb > Wn - 4) {           // only x0==112, k==5: replicate col W-1
            const float s0 = fmap[rowb + Wn - 1], s1 = fmap[rowb + HWn + Wn - 1];
            va.x = va.y = va.z = va.w = s0;
            vb.x = vb.y = vb.z = vb.w = s1;
        } else {
            va = *(const float4*)&fmap[rowb + gxb];
            vb = *(const float4*)&fmap[rowb + HWn + gxb];
        }
        unsigned short* hbase = &hs[(dy * HX + 4 * k) * RS + 2 * cp];
        *(unsigned*)&hbase[0 * RS] = (unsigned)f2bf(va.x) | ((unsigned)f2bf(vb.x) << 16);
        *(unsigned*)&hbase[1 * RS] = (unsigned)f2bf(va.y) | ((unsigned)f2bf(vb.y) << 16);
        *(unsigned*)&hbase[2 * RS] = (unsigned)f2bf(va.z) | ((unsigned)f2bf(vb.z) << 16);
        *(unsigned*)&hbase[3 * RS] = (unsigned)f2bf(va.w) | ((unsigned)f2bf(vb.w) << 16);
    }
    // stage attn: per yi-row, 400 contiguous floats; fully linear/coalesced.
    // at_s[p*25+l] = at_s[yi*400 + (xi*25+l)] == attn[(rowbase)*25 + j].
    {
        const size_t ab = ((size_t)b * HWn + (size_t)y0 * Wn + x0) * Ln;
        for (int i = tid; i < TY * TX * Ln; i += 256) {
            const int yi = i / 400, j = i - yi * 400;
            at_s[i] = attn[ab + (size_t)yi * (Wn * Ln) + j];
        }
    }
    __syncthreads();

    // ---- phase 1: 5x5 stencil (verbatim verified inner loop) ----
    // thread map: xi = tid&15, kq = (tid>>4)&3 (32-ch group), yi = tid>>6
    const int xi = tid & 15, kq = (tid >> 4) & 3, yi = tid >> 6;
    const int p = yi * 16 + xi;
    float acc[32];
#pragma unroll
    for (int j = 0; j < 32; ++j) acc[j] = 0.f;

#pragma unroll
    for (int l = 0; l < Ln; ++l) {
        const int dy = l / 5, dx = l % 5;
        const float a = at_s[p * Ln + l];
        const unsigned short* row = &hs[((yi + dy) * HX + (2 + xi + dx)) * RS + kq * 32];
#pragma unroll
        for (int q = 0; q < 4; ++q) {
            uint4 u = *(const uint4*)&row[q * 8];
            const unsigned w[4] = {u.x, u.y, u.z, u.w};
#pragma unroll
            for (int e = 0; e < 4; ++e) {
                acc[q * 8 + 2 * e + 0] += a * __uint_as_float(w[e] << 16);
                acc[q * 8 + 2 * e + 1] += a * __uint_as_float(w[e] & 0xffff0000u);
            }
        }
    }
    // pack acc -> sv tile (bf16, k-contiguous per pixel); no barrier needed yet
    {
        unsigned short* dst = &sv[p * SVS + kq * 32];
#pragma unroll
        for (int q = 0; q < 4; ++q) {
            unsigned pk[4];
#pragma unroll
            for (int e = 0; e < 4; ++e)
                pk[e] = (unsigned)f2bf(acc[q * 8 + 2 * e]) |
                        ((unsigned)f2bf(acc[q * 8 + 2 * e + 1]) << 16);
            uint4 v; v.x = pk[0]; v.y = pk[1]; v.z = pk[2]; v.w = pk[3];
            *(uint4*)&dst[q * 8] = v;
        }
    }
    // prefetch Wv f32 (coalesced; 64KB, L2-hot across all blocks)
    float4 wq[16];
#pragma unroll
    for (int t = 0; t < 16; ++t)
        wq[t] = *(const float4*)&Wv[(size_t)(tid + t * 256) * 4];

    __syncthreads();  // halo reads done everywhere; sv writes visible

    // ---- phase 2a: Wv -> bf16 into dead hs region ----
#pragma unroll
    for (int t = 0; t < 16; ++t) {
        const int i4 = tid + t * 256;      // float4 index within Wv
        const int r = i4 >> 5;             // row (32 float4 per 128-col row)
        const int c = (i4 & 31) * 4;
        uint2 v;
        v.x = (unsigned)f2bf(wq[t].x) | ((unsigned)f2bf(wq[t].y) << 16);
        v.y = (unsigned)f2bf(wq[t].z) | ((unsigned)f2bf(wq[t].w) << 16);
        *(uint2*)&hs[r * WVS + c] = v;
    }
    __syncthreads();

    // ---- phase 2b: MFMA, verified lsa_gemm mapping (wave = 16 px x 128 ch) ----
    const int wave = tid >> 6, lane = tid & 63;
    const int m16 = lane & 15, q = lane >> 4;
    const int n = (y0 + wave) * Wn + x0 + m16;  // wave w owns pixel row y0+w
    const float g = gamma[0];

    short8 bfrag[4];
    {
        const unsigned short* srow = &sv[(wave * 16 + m16) * SVS + q * 8];
#pragma unroll
        for (int kk = 0; kk < 4; ++kk) bfrag[kk] = *(const short8*)(srow + kk * 32);
    }
    f32x4 accv[8];
#pragma unroll
    for (int t = 0; t < 8; ++t) { f32x4 z = {0.f, 0.f, 0.f, 0.f}; accv[t] = z; }

#pragma unroll
    for (int t = 0; t < 8; ++t) {
        const unsigned short* arow = &hs[(t * 16 + m16) * WVS + q * 8];
#pragma unroll
        for (int kk = 0; kk < 4; ++kk) {
            short8 af = *(const short8*)(arow + kk * 32);
            accv[t] = __builtin_amdgcn_mfma_f32_16x16x32_bf16(af, bfrag[kk], accv[t], 0, 0, 0);
        }
    }

    // ---- phase 3: residual epilogue (f32 fmap from global, L2-hot) ----
#pragma unroll
    for (int t = 0; t < 8; ++t) {
#pragma unroll
        for (int r = 0; r < 4; ++r) {
            const int c = t * 16 + q * 4 + r;
            const size_t idx = ((size_t)(b * Cn + c)) * HWn + n;
            out[idx] = fmap[idx] + g * accv[t][r];
        }
    }
}
}  // namespace

extern "C" void kernel_launch(void* const* d_in, const int* in_sizes, int n_in,
                              void* d_out, int out_size, void* d_ws, size_t ws_size,
                              hipStream_t stream) {
    const float* attn  = (const float*)d_in[0];
    const float* fmap  = (const float*)d_in[1];
    const float* Wv    = (const float*)d_in[2];
    const float* gamma = (const float*)d_in[3];
    float* out = (float*)d_out;

    dim3 grid(Wn / TX, Hn / TY, Bn);  // 8 x 16 x 4 = 512 blocks
    lsa_fused<<<grid, 256, 0, stream>>>(attn, fmap, Wv, gamma, out);
}

// Round 3
// 98.974 us; speedup vs baseline: 1.1491x; 1.0077x over previous
//
#include <hip/hip_runtime.h>

// Fully-fused LSA, 512-thread variant. R2 (43us kernel) had all pipes idle
// (VALUBusy 17%, HBM 16%, Occ 21%) -> latency-bound at 2 waves/SIMD (76KB LDS
// caps 2 blocks/CU; grid is 512 blocks = 2/CU resident regardless). R3 keeps
// tile/layouts/numerics identical but runs 8 waves/block (512 thr) -> 4
// waves/SIMD, 2x latency hiding in every phase. Per-thread work halves:
// stencil owns 16 ch (kq 0..7), MFMA wave owns 16px x 64ch (verified R2-K2
// mhalf mapping). Wv f32 reg-prefetch dropped (VGPR budget; L2-hot load after
// barrier instead).
//   phase 0: halo fmap f32 -> hs bf16 [px][c] via float4 ch-pair staging
//            + stage attn (linear coalesced)
//   phase 1: 5x5 stencil, acc f32[16]/thread (8 thr/px) -> pack -> sv (LDS)
//   phase 2: cvt Wv -> bf16 into dead hs region; per-wave 16px x 64ch MFMA
//   phase 3: out = fmap + gamma * acc   (f32 residual from global)
// B=4, C=128, H=64, W=128, L=25. LDS 76.0 KB -> 2 blocks/CU, 16 waves/CU.

namespace {
constexpr int Bn = 4, Cn = 128, Hn = 64, Wn = 128, Ln = 25;
constexpr int HWn = Hn * Wn;  // 8192

constexpr int TY = 4, TX = 16;   // output tile: 64 px/block
constexpr int HY = 8, HX = 24;   // halo rows x cols (y0-2..y0+5, x0-4..x0+19)
constexpr int RS = 136;          // hs row stride in halves (272B, 16B-aligned)
constexpr int SVS = 136;         // sv row stride in halves
constexpr int WVS = 136;         // wv row stride in halves (hs region reuse)
constexpr int NT = 512;          // threads/block

typedef __attribute__((ext_vector_type(8))) short short8;
typedef __attribute__((ext_vector_type(4))) float f32x4;

__device__ inline unsigned short f2bf(float f) {
    unsigned u = __float_as_uint(f);
    return (unsigned short)((u + 0x7fffu + ((u >> 16) & 1u)) >> 16);  // RNE
}

__global__ __launch_bounds__(NT, 4) void lsa_fused(
    const float* __restrict__ attn, const float* __restrict__ fmap,
    const float* __restrict__ Wv, const float* __restrict__ gamma,
    float* __restrict__ out)
{
    // hs: halo bf16 [px = dy*HX+hx][c] (52.2 KB) -- reused for Wv bf16 later
    __shared__ alignas(16) unsigned short hs[HY * HX * RS];
    __shared__ alignas(16) unsigned short sv[TY * TX * SVS];  // 17.4 KB
    __shared__ float at_s[TY * TX * Ln];                      // 6.4 KB

    const int tid = threadIdx.x;
    const int b = blockIdx.z;
    const int x0 = blockIdx.x * TX;
    const int y0 = blockIdx.y * TY;

    // ---- phase 0: halo stage, channel-pair float4 runs (f32 -> packed bf16) ----
    // work item i -> (k = gx-quad 0..5, cp = channel-pair 0..63, dy = 0..7).
    // Global side ~11 contiguous 96B runs per wave-instr. Halo quads are fully
    // in-range or fully clamped (W mult of 4, pad 4). 6 iters/thread.
    for (int i = tid; i < HY * 64 * 6; i += NT) {
        const int k = i % 6;
        const int r = i / 6;
        const int cp = r & 63;
        const int dy = r >> 6;
        const int ry = min(max(y0 + dy - 2, 0), Hn - 1);
        const int gxb = x0 - 4 + 4 * k;
        const size_t rowb = ((size_t)(b * Cn + 2 * cp)) * HWn + (size_t)ry * Wn;
        float4 va, vb;
        if (gxb < 0) {                       // only x0==0, k==0: replicate col 0
            const float s0 = fmap[rowb], s1 = fmap[rowb + HWn];
            va.x = va.y = va.z = va.w = s0;
            vb.x = vb.y = vb.z = vb.w = s1;
        } else if (gxb > Wn - 4) {           // only x0==112, k==5: replicate col W-1
            const float s0 = fmap[rowb + Wn - 1], s1 = fmap[rowb + HWn + Wn - 1];
            va.x = va.y = va.z = va.w = s0;
            vb.x = vb.y = vb.z = vb.w = s1;
        } else {
            va = *(const float4*)&fmap[rowb + gxb];
            vb = *(const float4*)&fmap[rowb + HWn + gxb];
        }
        unsigned short* hbase = &hs[(dy * HX + 4 * k) * RS + 2 * cp];
        *(unsigned*)&hbase[0 * RS] = (unsigned)f2bf(va.x) | ((unsigned)f2bf(vb.x) << 16);
        *(unsigned*)&hbase[1 * RS] = (unsigned)f2bf(va.y) | ((unsigned)f2bf(vb.y) << 16);
        *(unsigned*)&hbase[2 * RS] = (unsigned)f2bf(va.z) | ((unsigned)f2bf(vb.z) << 16);
        *(unsigned*)&hbase[3 * RS] = (unsigned)f2bf(va.w) | ((unsigned)f2bf(vb.w) << 16);
    }
    // stage attn: per yi-row, 400 contiguous floats; fully linear/coalesced.
    {
        const size_t ab = ((size_t)b * HWn + (size_t)y0 * Wn + x0) * Ln;
        for (int i = tid; i < TY * TX * Ln; i += NT) {
            const int yi = i / 400, j = i - yi * 400;
            at_s[i] = attn[ab + (size_t)yi * (Wn * Ln) + j];
        }
    }
    __syncthreads();

    // ---- phase 1: 5x5 stencil (verified inner loop; 16 ch/thread) ----
    // thread map: xi = tid&15, kq = (tid>>4)&7 (16-ch group), yi = tid>>7
    const int xi = tid & 15, kq = (tid >> 4) & 7, yi = tid >> 7;
    const int p = yi * 16 + xi;
    float acc[16];
#pragma unroll
    for (int j = 0; j < 16; ++j) acc[j] = 0.f;

#pragma unroll
    for (int l = 0; l < Ln; ++l) {
        const int dy = l / 5, dx = l % 5;
        const float a = at_s[p * Ln + l];
        const unsigned short* row = &hs[((yi + dy) * HX + (2 + xi + dx)) * RS + kq * 16];
#pragma unroll
        for (int q = 0; q < 2; ++q) {
            uint4 u = *(const uint4*)&row[q * 8];
            const unsigned w[4] = {u.x, u.y, u.z, u.w};
#pragma unroll
            for (int e = 0; e < 4; ++e) {
                acc[q * 8 + 2 * e + 0] += a * __uint_as_float(w[e] << 16);
                acc[q * 8 + 2 * e + 1] += a * __uint_as_float(w[e] & 0xffff0000u);
            }
        }
    }
    // pack acc -> sv tile (bf16, k-contiguous per pixel); no barrier needed yet
    {
        unsigned short* dst = &sv[p * SVS + kq * 16];
#pragma unroll
        for (int q = 0; q < 2; ++q) {
            unsigned pk[4];
#pragma unroll
            for (int e = 0; e < 4; ++e)
                pk[e] = (unsigned)f2bf(acc[q * 8 + 2 * e]) |
                        ((unsigned)f2bf(acc[q * 8 + 2 * e + 1]) << 16);
            uint4 v; v.x = pk[0]; v.y = pk[1]; v.z = pk[2]; v.w = pk[3];
            *(uint4*)&dst[q * 8] = v;
        }
    }
    __syncthreads();  // halo reads done everywhere; sv writes visible

    // ---- phase 2a: Wv (L2-hot, same 64KB all blocks) -> bf16 into dead hs ----
#pragma unroll
    for (int t = 0; t < 8; ++t) {
        const int i4 = tid + t * NT;       // float4 index within Wv
        const float4 w = *(const float4*)&Wv[(size_t)i4 * 4];
        const int r = i4 >> 5;             // row (32 float4 per 128-col row)
        const int c = (i4 & 31) * 4;
        uint2 v;
        v.x = (unsigned)f2bf(w.x) | ((unsigned)f2bf(w.y) << 16);
        v.y = (unsigned)f2bf(w.z) | ((unsigned)f2bf(w.w) << 16);
        *(uint2*)&hs[r * WVS + c] = v;
    }
    __syncthreads();

    // ---- phase 2b: MFMA; wave = 16 px x 64 ch (verified R2-K2 mhalf map) ----
    const int wave = tid >> 6, lane = tid & 63;
    const int m16 = lane & 15, q = lane >> 4;
    const int wrow = wave >> 1;            // pixel row yi
    const int mhalf = wave & 1;            // 64-channel half
    const int n = (y0 + wrow) * Wn + x0 + m16;
    const float g = gamma[0];

    short8 bfrag[4];
    {
        const unsigned short* srow = &sv[(wrow * 16 + m16) * SVS + q * 8];
#pragma unroll
        for (int kk = 0; kk < 4; ++kk) bfrag[kk] = *(const short8*)(srow + kk * 32);
    }
    f32x4 accv[4];
#pragma unroll
    for (int t = 0; t < 4; ++t) { f32x4 z = {0.f, 0.f, 0.f, 0.f}; accv[t] = z; }

#pragma unroll
    for (int t = 0; t < 4; ++t) {
        const int mg = mhalf * 4 + t;
        const unsigned short* arow = &hs[(mg * 16 + m16) * WVS + q * 8];
#pragma unroll
        for (int kk = 0; kk < 4; ++kk) {
            short8 af = *(const short8*)(arow + kk * 32);
            accv[t] = __builtin_amdgcn_mfma_f32_16x16x32_bf16(af, bfrag[kk], accv[t], 0, 0, 0);
        }
    }

    // ---- phase 3: residual epilogue (f32 fmap from global, L2/L3-hot) ----
#pragma unroll
    for (int t = 0; t < 4; ++t) {
        const int mg = mhalf * 4 + t;
#pragma unroll
        for (int r = 0; r < 4; ++r) {
            const int c = mg * 16 + q * 4 + r;
            const size_t idx = ((size_t)(b * Cn + c)) * HWn + n;
            out[idx] = fmap[idx] + g * accv[t][r];
        }
    }
}
}  // namespace

extern "C" void kernel_launch(void* const* d_in, const int* in_sizes, int n_in,
                              void* d_out, int out_size, void* d_ws, size_t ws_size,
                              hipStream_t stream) {
    const float* attn  = (const float*)d_in[0];
    const float* fmap  = (const float*)d_in[1];
    const float* Wv    = (const float*)d_in[2];
    const float* gamma = (const float*)d_in[3];
    float* out = (float*)d_out;

    dim3 grid(Wn / TX, Hn / TY, Bn);  // 8 x 16 x 4 = 512 blocks
    lsa_fused<<<grid, NT, 0, stream>>>(attn, fmap, Wv, gamma, out);
}

// Round 5
// 90.204 us; speedup vs baseline: 1.2608x; 1.0972x over previous
//
#include <hip/hip_runtime.h>

// Fully-fused LSA, R5 = R4 with the Wv staging bug fixed (R4 loaded only 2
// float4/thread of Wv instead of 8 -> 3/4 of the Wv LDS tile was garbage,
// absmax 660). All R4 structural changes retained:
//  (1) XCD-aware block swizzle: hw bid%8 -> XCD; each XCD gets 64 consecutive
//      logical blocks (one batch x 32-row band, fmap slice 2.4MB < 4MB L2) so
//      halo overlap + epilogue fmap re-reads hit L2 on poison-cold caches.
//  (2) Phase 0 stages all 12 halo float4 loads into REGISTERS before any LDS
//      write -> 12 outstanding HBM misses/thread.
//  (3) attn staged as one float4/thread (linear); Wv (8 float4/thread) issued
//      to regs while the stencil accumulator drains.
// Stencil / sv pack / MFMA / epilogue index algebra verbatim R3 (verified,
// absmax 0.125). B=4, C=128, H=64, W=128, L=25. LDS 76.0 KB -> 2 blocks/CU.

namespace {
constexpr int Bn = 4, Cn = 128, Hn = 64, Wn = 128, Ln = 25;
constexpr int HWn = Hn * Wn;  // 8192

constexpr int TY = 4, TX = 16;   // output tile: 64 px/block
constexpr int HY = 8, HX = 24;   // halo rows x cols (y0-2..y0+5, x0-4..x0+19)
constexpr int RS = 136;          // hs row stride in halves (272B, 16B-aligned)
constexpr int SVS = 136;         // sv row stride in halves
constexpr int WVS = 136;         // wv row stride in halves (hs region reuse)
constexpr int NT = 512;          // threads/block

typedef __attribute__((ext_vector_type(8))) short short8;
typedef __attribute__((ext_vector_type(4))) float f32x4;

__device__ inline unsigned short f2bf(float f) {
    unsigned u = __float_as_uint(f);
    return (unsigned short)((u + 0x7fffu + ((u >> 16) & 1u)) >> 16);  // RNE
}

__global__ __launch_bounds__(NT, 4) void lsa_fused(
    const float* __restrict__ attn, const float* __restrict__ fmap,
    const float* __restrict__ Wv, const float* __restrict__ gamma,
    float* __restrict__ out)
{
    // hs: halo bf16 [px = dy*HX+hx][c] (52.2 KB) -- reused for Wv bf16 later
    __shared__ alignas(16) unsigned short hs[HY * HX * RS];
    __shared__ alignas(16) unsigned short sv[TY * TX * SVS];  // 17.4 KB
    __shared__ alignas(16) float at_s[TY * TX * Ln];          // 6.4 KB

    const int tid = threadIdx.x;

    // XCD swizzle: hw XCD = bid % 8; give each XCD 64 consecutive LOGICAL
    // blocks (= one batch, 32-row band, all x) for L2 halo sharing. Bijective.
    const unsigned bid = blockIdx.x;                 // 0..511
    const unsigned logical = (bid & 7u) * 64u + (bid >> 3);
    const int bx  = logical & 7;       // 8 x-tiles
    const int byz = logical >> 3;
    const int by  = byz & 15;          // 16 y-tiles
    const int b   = byz >> 4;          // 4 batches
    const int x0 = bx * TX;
    const int y0 = by * TY;

    // ---- phase 0a: ISSUE all halo loads into regs (12 float4 in flight) ----
    // item i -> (k = gx-quad 0..5, cp = channel-pair 0..63, dy = 0..7).
    // Halo quads are fully in-range or fully clamped (W mult of 4, pad 4).
    float4 va[6], vb[6];
#pragma unroll
    for (int t = 0; t < 6; ++t) {
        const int i = tid + t * NT;            // 3072 items exactly
        const int k = i % 6;
        const int r = i / 6;
        const int cp = r & 63;
        const int dy = r >> 6;
        const int ry = min(max(y0 + dy - 2, 0), Hn - 1);
        const int gxb = x0 - 4 + 4 * k;
        const size_t rowb = ((size_t)(b * Cn + 2 * cp)) * HWn + (size_t)ry * Wn;
        if (gxb < 0) {                       // only bx==0, k==0: replicate col 0
            const float s0 = fmap[rowb], s1 = fmap[rowb + HWn];
            va[t].x = va[t].y = va[t].z = va[t].w = s0;
            vb[t].x = vb[t].y = vb[t].z = vb[t].w = s1;
        } else if (gxb > Wn - 4) {           // only bx==7, k==5: replicate col W-1
            const float s0 = fmap[rowb + Wn - 1], s1 = fmap[rowb + HWn + Wn - 1];
            va[t].x = va[t].y = va[t].z = va[t].w = s0;
            vb[t].x = vb[t].y = vb[t].z = vb[t].w = s1;
        } else {
            va[t] = *(const float4*)&fmap[rowb + gxb];
            vb[t] = *(const float4*)&fmap[rowb + HWn + gxb];
        }
    }
    // issue attn load (1 float4 for tid<400): at_s linear == global linear/row
    float4 at_r;
    const int yi_a = tid / 100, j4 = tid - yi_a * 100;
    if (tid < 400) {
        const size_t ab = ((size_t)b * HWn + (size_t)y0 * Wn + x0) * Ln;
        at_r = *(const float4*)&attn[ab + (size_t)yi_a * (Wn * Ln) + j4 * 4];
    }

    // ---- phase 0b: drain to LDS (packed bf16, same hs layout as R2/R3) ----
#pragma unroll
    for (int t = 0; t < 6; ++t) {
        const int i = tid + t * NT;
        const int k = i % 6;
        const int r = i / 6;
        const int cp = r & 63;
        const int dy = r >> 6;
        unsigned short* hbase = &hs[(dy * HX + 4 * k) * RS + 2 * cp];
        *(unsigned*)&hbase[0 * RS] = (unsigned)f2bf(va[t].x) | ((unsigned)f2bf(vb[t].x) << 16);
        *(unsigned*)&hbase[1 * RS] = (unsigned)f2bf(va[t].y) | ((unsigned)f2bf(vb[t].y) << 16);
        *(unsigned*)&hbase[2 * RS] = (unsigned)f2bf(va[t].z) | ((unsigned)f2bf(vb[t].z) << 16);
        *(unsigned*)&hbase[3 * RS] = (unsigned)f2bf(va[t].w) | ((unsigned)f2bf(vb[t].w) << 16);
    }
    if (tid < 400) *(float4*)&at_s[tid * 4] = at_r;
    __syncthreads();

    // ---- phase 1: 5x5 stencil (verbatim R3; 16 ch/thread) ----
    // thread map: xi = tid&15, kq = (tid>>4)&7 (16-ch group), yi = tid>>7
    const int xi = tid & 15, kq = (tid >> 4) & 7, yi = tid >> 7;
    const int p = yi * 16 + xi;
    float acc[16];
#pragma unroll
    for (int j = 0; j < 16; ++j) acc[j] = 0.f;

#pragma unroll
    for (int l = 0; l < Ln; ++l) {
        const int dy = l / 5, dx = l % 5;
        const float a = at_s[p * Ln + l];
        const unsigned short* row = &hs[((yi + dy) * HX + (2 + xi + dx)) * RS + kq * 16];
#pragma unroll
        for (int q = 0; q < 2; ++q) {
            uint4 u = *(const uint4*)&row[q * 8];
            const unsigned w[4] = {u.x, u.y, u.z, u.w};
#pragma unroll
            for (int e = 0; e < 4; ++e) {
                acc[q * 8 + 2 * e + 0] += a * __uint_as_float(w[e] << 16);
                acc[q * 8 + 2 * e + 1] += a * __uint_as_float(w[e] & 0xffff0000u);
            }
        }
    }
    // issue Wv loads now (8 float4/thread = full 128x128; latency hides under
    // the sv pack + barrier)
    float4 wq[8];
#pragma unroll
    for (int t = 0; t < 8; ++t)
        wq[t] = *(const float4*)&Wv[(size_t)(tid + t * NT) * 4];

    // pack acc -> sv tile (bf16, k-contiguous per pixel)
    {
        unsigned short* dst = &sv[p * SVS + kq * 16];
#pragma unroll
        for (int q = 0; q < 2; ++q) {
            unsigned pk[4];
#pragma unroll
            for (int e = 0; e < 4; ++e)
                pk[e] = (unsigned)f2bf(acc[q * 8 + 2 * e]) |
                        ((unsigned)f2bf(acc[q * 8 + 2 * e + 1]) << 16);
            uint4 v; v.x = pk[0]; v.y = pk[1]; v.z = pk[2]; v.w = pk[3];
            *(uint4*)&dst[q * 8] = v;
        }
    }
    __syncthreads();  // halo reads done everywhere; sv writes visible

    // ---- phase 2a: Wv -> bf16 into dead hs region (full 16384 floats) ----
#pragma unroll
    for (int t = 0; t < 8; ++t) {
        const int i4 = tid + t * NT;       // float4 index within Wv, 0..4095
        const int r = i4 >> 5;             // row (32 float4 per 128-col row)
        const int c = (i4 & 31) * 4;
        uint2 v;
        v.x = (unsigned)f2bf(wq[t].x) | ((unsigned)f2bf(wq[t].y) << 16);
        v.y = (unsigned)f2bf(wq[t].z) | ((unsigned)f2bf(wq[t].w) << 16);
        *(uint2*)&hs[r * WVS + c] = v;
    }
    __syncthreads();

    // ---- phase 2b: MFMA; wave = 16 px x 64 ch (verified R2-K2 mhalf map) ----
    const int wave = tid >> 6, lane = tid & 63;
    const int m16 = lane & 15, q = lane >> 4;
    const int wrow = wave >> 1;            // pixel row yi
    const int mhalf = wave & 1;            // 64-channel half
    const int n = (y0 + wrow) * Wn + x0 + m16;
    const float g = gamma[0];

    short8 bfrag[4];
    {
        const unsigned short* srow = &sv[(wrow * 16 + m16) * SVS + q * 8];
#pragma unroll
        for (int kk = 0; kk < 4; ++kk) bfrag[kk] = *(const short8*)(srow + kk * 32);
    }
    f32x4 accv[4];
#pragma unroll
    for (int t = 0; t < 4; ++t) { f32x4 z = {0.f, 0.f, 0.f, 0.f}; accv[t] = z; }

#pragma unroll
    for (int t = 0; t < 4; ++t) {
        const int mg = mhalf * 4 + t;
        const unsigned short* arow = &hs[(mg * 16 + m16) * WVS + q * 8];
#pragma unroll
        for (int kk = 0; kk < 4; ++kk) {
            short8 af = *(const short8*)(arow + kk * 32);
            accv[t] = __builtin_amdgcn_mfma_f32_16x16x32_bf16(af, bfrag[kk], accv[t], 0, 0, 0);
        }
    }

    // ---- phase 3: residual epilogue (fmap L2-hot via swizzle) ----
#pragma unroll
    for (int t = 0; t < 4; ++t) {
        const int mg = mhalf * 4 + t;
#pragma unroll
        for (int r = 0; r < 4; ++r) {
            const int c = mg * 16 + q * 4 + r;
            const size_t idx = ((size_t)(b * Cn + c)) * HWn + n;
            out[idx] = fmap[idx] + g * accv[t][r];
        }
    }
}
}  // namespace

extern "C" void kernel_launch(void* const* d_in, const int* in_sizes, int n_in,
                              void* d_out, int out_size, void* d_ws, size_t ws_size,
                              hipStream_t stream) {
    const float* attn  = (const float*)d_in[0];
    const float* fmap  = (const float*)d_in[1];
    const float* Wv    = (const float*)d_in[2];
    const float* gamma = (const float*)d_in[3];
    float* out = (float*)d_out;

    lsa_fused<<<dim3(512), NT, 0, stream>>>(attn, fmap, Wv, gamma, out);
}